// Round 9
// baseline (237.422 us; speedup 1.0000x reference)
//
#include <hip/hip_runtime.h>

#define NTOK 4096
#define DIM 1024
#define NE 8
#define NPAIR (NTOK * 2)
#define GATE_BLOCKS (NTOK / 4)   // 1024
#define CVT_BLOCKS 8192          // one tensor: 8M float4 / 256 thr / 4 per thr
#define NBIN (NTOK / 256)        // 16
#define GRID 576                 // 8 xcd x 9 slots x 8 nt

typedef __bf16 bf16x8 __attribute__((ext_vector_type(8)));
typedef float floatx4 __attribute__((ext_vector_type(4)));

__device__ __forceinline__ unsigned short f2bf(float f) {
  unsigned u = __float_as_uint(f);
  u = u + 0x7fffu + ((u >> 16) & 1u);
  return (unsigned short)(u >> 16);
}
__device__ __forceinline__ float bf2f(unsigned short h) {
  return __uint_as_float(((unsigned)h) << 16);
}

__device__ __forceinline__ void gld_lds16(const unsigned short* g, unsigned short* l) {
  __builtin_amdgcn_global_load_lds(
      (const __attribute__((address_space(1))) void*)g,
      (__attribute__((address_space(3))) void*)l, 16, 0, 0);
}

// ---------------- prep: gate (blocks 0..1023, FIRST so bin's dep finishes early) -------
// + w1 cvt (blocks 1024..9215). Gate: one wave per token; emits x_bf, tops, pairw, gp;
// ZEROES its token's y row (required by gemm2's atomic-accumulate epilogue).
// Block 0 zeroes cnt[0..7]+done.
__global__ __launch_bounds__(256) void prep_kernel(
    const float4* __restrict__ w1, ushort4* __restrict__ w1_bf,
    const float* __restrict__ x, const float* __restrict__ gW,
    const float* __restrict__ gb, float* __restrict__ gp_out,
    int2* __restrict__ tops, float* __restrict__ pairw,
    int* __restrict__ cnt, unsigned short* __restrict__ x_bf,
    float* __restrict__ y)
{
  const int tid = threadIdx.x;
  int b = blockIdx.x;
  if (b >= GATE_BLOCKS) {                     // -------- cvt w1 branch --------
    const int i = (b - GATE_BLOCKS) * 256 + tid;
    float4 v = w1[i];
    ushort4 o;
    o.x = f2bf(v.x); o.y = f2bf(v.y); o.z = f2bf(v.z); o.w = f2bf(v.w);
    w1_bf[i] = o;
    return;
  }
  // -------- gate branch (R2-proven) --------
  if (b == 0 && tid < NE + 1) cnt[tid] = 0;   // cnt[0..7] + done
  const int lane = tid & 63;
  const int wid = tid >> 6;
  const int t = b * 4 + wid;

  float4 xv[4];
#pragma unroll
  for (int j = 0; j < 4; j++)
    xv[j] = ((const float4*)(x + (size_t)t * DIM))[lane + 64 * j];

  // zero y row (atomic-accumulate target) + bf16 copy of x row
  const float4 z4 = make_float4(0.f, 0.f, 0.f, 0.f);
#pragma unroll
  for (int j = 0; j < 4; j++) {
    ((float4*)(y + (size_t)t * DIM))[lane + 64 * j] = z4;
    ushort4 o;
    o.x = f2bf(xv[j].x); o.y = f2bf(xv[j].y);
    o.z = f2bf(xv[j].z); o.w = f2bf(xv[j].w);
    ((ushort4*)(x_bf + (size_t)t * DIM))[lane + 64 * j] = o;
  }

  float p[NE];
#pragma unroll
  for (int e = 0; e < NE; e++) {
    const float4* gwe = (const float4*)(gW + e * DIM);
    float s = 0.f;
#pragma unroll
    for (int j = 0; j < 4; j++) {
      float4 g = gwe[lane + 64 * j];
      s += xv[j].x * g.x + xv[j].y * g.y + xv[j].z * g.z + xv[j].w * g.w;
    }
    p[e] = s;
  }
#pragma unroll
  for (int e = 0; e < NE; e++) {
#pragma unroll
    for (int off = 32; off >= 1; off >>= 1) p[e] += __shfl_xor(p[e], off);
  }

  float m = -1e30f;
#pragma unroll
  for (int e = 0; e < NE; e++) { p[e] += gb[e]; m = fmaxf(m, p[e]); }
  float s = 0.f;
  float pr[NE];
#pragma unroll
  for (int e = 0; e < NE; e++) { pr[e] = __expf(p[e] - m); s += pr[e]; }
  float inv = 1.f / s;
#pragma unroll
  for (int e = 0; e < NE; e++) pr[e] *= inv;

  if (lane < NE) gp_out[(size_t)t * NE + lane] = pr[lane];

  if (lane == 0) {
    int i0 = 0;
#pragma unroll
    for (int e = 1; e < NE; e++) if (pr[e] > pr[i0]) i0 = e;
    int i1 = (i0 == 0) ? 1 : 0;
#pragma unroll
    for (int e = 0; e < NE; e++) if (e != i0 && pr[e] > pr[i1]) i1 = e;
    float d = __expf(pr[i1] - pr[i0]);
    float w0 = 1.f / (1.f + d);
    tops[t] = make_int2(i0, i1);
    pairw[t * 2] = w0;
    pairw[t * 2 + 1] = 1.f - w0;
  }
}

// ------- binning + schedule: wave-aggregated ballot atomics (R2-proven) ----------------
__global__ __launch_bounds__(256) void bin_sched_kernel(
    const int2* __restrict__ tops, int* __restrict__ cnt,
    int* __restrict__ bucket,      // [NE][NTOK]: pair id per within-expert index
    int* __restrict__ posmap,      // [NPAIR]: (e<<16)|idx (kept for debug/ABI stability)
    int* __restrict__ done, int* __restrict__ base,   // base[9]
    int* __restrict__ sched, int* __restrict__ sched_n)
{
  const int t = blockIdx.x * 256 + threadIdx.x;
  const int lane = threadIdx.x & 63;
  int2 ti = tops[t];
#pragma unroll
  for (int slot = 0; slot < 2; slot++) {
    int e = slot ? ti.y : ti.x;
#pragma unroll
    for (int ex = 0; ex < NE; ex++) {
      bool mine = (e == ex);
      unsigned long long mask = __ballot(mine);
      if (mask) {
        int leader = __ffsll((long long)mask) - 1;
        int total = __popcll(mask);
        int prefix = __popcll(mask & ((1ull << lane) - 1ull));
        int idx = 0;
        if (lane == leader) idx = atomicAdd(&cnt[ex], total);
        idx = __shfl(idx, leader) + prefix;
        if (mine) {
          bucket[ex * NTOK + idx] = t * 2 + slot;
          posmap[t * 2 + slot] = (ex << 16) | idx;
        }
      }
    }
  }
  __syncthreads();
  if (threadIdx.x == 0) {
    if (atomicAdd(done, 1) == gridDim.x - 1) {   // last block: build schedule
      int b = 0, pos = 0;
      for (int e = 0; e < NE; e++) {
        int c = atomicAdd(&cnt[e], 0);           // device-coherent read
        base[e] = b;
        int tiles = (c + 127) >> 7;
        for (int i = 0; i < tiles; i++) {
          int valid = c - i * 128; if (valid > 128) valid = 128;
          sched[pos++] = (e << 20) | (i << 8) | valid;
        }
        b += c;
      }
      base[NE] = b;
      *sched_n = pos;
    }
  }
}

// ---------------- fp32 -> bf16 conversion of w2 (runs AFTER gemm1, into w1_bf's region)
__global__ __launch_bounds__(256) void cvt_kernel(
    const float4* __restrict__ src, ushort4* __restrict__ dst)
{
  const int i = blockIdx.x * 256 + threadIdx.x;
  float4 v = src[i];
  ushort4 o;
  o.x = f2bf(v.x); o.y = f2bf(v.y); o.z = f2bf(v.z); o.w = f2bf(v.w);
  dst[i] = o;
}

// -------- grouped GEMM: 128x128 tile, BK=64, single-buffer, 4 WAVES (R7-proven loop) ---
// GATHER=1: A rows gathered from x_bf via bucket (gemm1); GATHER=0: packed rows.
// ATOMIC=0: Out[row][col] = f2bf(relu?(acc+bias)) (gemm1 -> h_pack).
// ATOMIC=1: y[tok][col] += pairw[pair] * (acc+bias) via fp32 atomicAdd (gemm2; y zeroed
//           by prep). Each y element receives exactly 2 adds; fp32 order noise ~1ulp.
template <int RELU, int GATHER, int ATOMIC>
__global__ __launch_bounds__(256) void ffn_gemm(
    const unsigned short* __restrict__ A,     // GATHER ? x_bf [NTOK][DIM] : packed [NPAIR][DIM]
    const unsigned short* __restrict__ B,     // [NE][DIM][DIM]
    const float* __restrict__ bias,           // [NE][DIM]
    const int* __restrict__ base,
    const int* __restrict__ bucket,
    const float* __restrict__ pairw,
    const int* __restrict__ sched, const int* __restrict__ sched_n,
    unsigned short* __restrict__ Out,         // ATOMIC=0 target
    float* __restrict__ yout)                 // ATOMIC=1 target
{
  const int l = blockIdx.x;
  const int xcd = l & 7;
  const int w = l >> 3;
  const int nt = w & 7;
  const int slot = xcd * 9 + (w >> 3);
  if (slot >= *sched_n) return;
  const int se = sched[slot];
  const int e = se >> 20;
  const int mt = (se >> 8) & 0xfff;
  const int valid = se & 255;               // valid rows in this tile (1..128)
  const int arow0 = base[e] + mt * 128;

  __shared__ unsigned short lda[128 * 64];  // 16 KB
  __shared__ unsigned short ldb[128 * 64];  // 16 KB (32 KB total -> 5 blocks/CU cap)

  const int tid = threadIdx.x;
  const int lane = tid & 63;
  const int wid = tid >> 6;

  const unsigned short* ap[4];
  const unsigned short* bp[4];
#pragma unroll
  for (int j = 0; j < 4; j++) {
    int g = wid * 4 + j;
    int row = g * 8 + (lane >> 3);
    int gran = (lane & 7) ^ (row & 7);      // source-side XOR swizzle (0 conflicts)
    if (GATHER) {
      int idx = mt * 128 + row;             // within-expert index
      int ce = base[e + 1] - base[e];       // expert count (>=1 if tile exists)
      if (idx > ce - 1) idx = ce - 1;       // clamp pad rows (masked at store)
      int tok = bucket[e * NTOK + idx] >> 1;
      ap[j] = A + (size_t)tok * DIM + (gran << 3);
    } else {
      int prow = arow0 + row;
      if (prow > NPAIR - 1) prow = NPAIR - 1;
      ap[j] = A + (size_t)prow * DIM + (gran << 3);
    }
    bp[j] = B + ((size_t)e * DIM + nt * 128 + row) * DIM + (gran << 3);
  }

  floatx4 acc[4][4] = {};
  const int wm = (wid & 1) * 64;
  const int wn = (wid >> 1) * 64;
  const int quad = lane >> 4;
  const int cl = lane & 15;
  const int sw = cl & 7;

  for (int k0 = 0; k0 < 16; k0++) {
#pragma unroll
    for (int j = 0; j < 4; j++) {
      int g = wid * 4 + j;
      gld_lds16(ap[j], &lda[g * 512]);
      gld_lds16(bp[j], &ldb[g * 512]);
      ap[j] += 64;
      bp[j] += 64;
    }
    __syncthreads();
#pragma unroll
    for (int kk = 0; kk < 64; kk += 32) {
      const int gb = (kk >> 3) + quad;
      const int goff = ((gb ^ sw) << 3);
      bf16x8 af[4], bfr[4];
#pragma unroll
      for (int mi = 0; mi < 4; mi++)
        af[mi] = *(const bf16x8*)&lda[(wm + mi * 16 + cl) * 64 + goff];
#pragma unroll
      for (int ni = 0; ni < 4; ni++)
        bfr[ni] = *(const bf16x8*)&ldb[(wn + ni * 16 + cl) * 64 + goff];
#pragma unroll
      for (int mi = 0; mi < 4; mi++)
#pragma unroll
        for (int ni = 0; ni < 4; ni++)
          acc[mi][ni] = __builtin_amdgcn_mfma_f32_16x16x32_bf16(af[mi], bfr[ni], acc[mi][ni], 0, 0, 0);
    }
    if (k0 < 15) __syncthreads();
  }

  // epilogue: C/D layout col=lane&15, row=(lane>>4)*4+reg [m89]
  if (ATOMIC) {
    float bval[4];
#pragma unroll
    for (int ni = 0; ni < 4; ni++) bval[ni] = bias[e * DIM + nt * 128 + wn + ni * 16 + cl];
#pragma unroll
    for (int mi = 0; mi < 4; mi++) {
#pragma unroll
      for (int reg = 0; reg < 4; reg++) {
        int rl = wm + mi * 16 + quad * 4 + reg;
        if (rl < valid) {
          int pairid = bucket[e * NTOK + mt * 128 + rl];
          float wgt = pairw[pairid];
          float* yrow = yout + (size_t)(pairid >> 1) * DIM + nt * 128 + wn;
#pragma unroll
          for (int ni = 0; ni < 4; ni++) {
            float v = acc[mi][ni][reg] + bval[ni];
            atomicAdd(&yrow[ni * 16 + cl], wgt * v);
          }
        }
      }
    }
  } else {
#pragma unroll
    for (int ni = 0; ni < 4; ni++) {
      int col = nt * 128 + wn + ni * 16 + cl;
      float bval = bias[e * DIM + col];
#pragma unroll
      for (int mi = 0; mi < 4; mi++) {
#pragma unroll
        for (int reg = 0; reg < 4; reg++) {
          int rl = wm + mi * 16 + quad * 4 + reg;
          if (rl < valid) {
            float v = acc[mi][ni][reg] + bval;
            if (RELU) v = fmaxf(v, 0.f);
            Out[(size_t)(arow0 + rl) * DIM + col] = f2bf(v);
          }
        }
      }
    }
  }
}

extern "C" void kernel_launch(void* const* d_in, const int* in_sizes, int n_in,
                              void* d_out, int out_size, void* d_ws, size_t ws_size,
                              hipStream_t stream) {
  const float* x  = (const float*)d_in[0];
  const float* gW = (const float*)d_in[1];
  const float* gb = (const float*)d_in[2];
  const float* w1 = (const float*)d_in[3];
  const float* b1 = (const float*)d_in[4];
  const float* w2 = (const float*)d_in[5];
  const float* b2 = (const float*)d_in[6];
  float* y  = (float*)d_out;
  float* gp = (float*)d_out + (size_t)NTOK * DIM;

  // ws layout (bytes) — peak 40M + ~230K (down from 56M: poison-fill is ~1.2 TB/s and
  // inside the timed graph, so every MB of ws costs ~0.85 µs/iter).
  //  [0,8M):    x_bf (prep->gemm1)
  //  [8,24M):   w1_bf (prep->gemm1 B) -> dead after gemm1 -> w2_bf (cvt->gemm2 B)
  //  [24,40M):  h_pack (gemm1 out -> gemm2 A)
  //  [40M,..):  cnt|done|base|sched|sched_n|bucket|pairw|tops|posmap
  char* ws = (char*)d_ws;
  unsigned short* x_bf   = (unsigned short*)(ws);
  unsigned short* w1_bf  = (unsigned short*)(ws + (size_t)(8u << 20));
  unsigned short* w2_bf  = (unsigned short*)(ws + (size_t)(8u << 20));  // alias, post-gemm1
  unsigned short* h_pack = (unsigned short*)(ws + (size_t)(24u << 20));
  char* tail = ws + (size_t)(40u << 20);
  int*   cnt     = (int*)(tail);                   // 8
  int*   done    = cnt + NE;                       // 1 (contiguous: cnt[8])
  int*   base    = done + 1;                       // 9
  int*   sched   = base + NE + 1;                  // <=256 (128-row tiles: up to 72)
  int*   sched_n = sched + 256;                    // 1
  int*   bucket  = sched_n + 1;                    // NE*NTOK
  float* pairw   = (float*)(bucket + NE * NTOK);   // NPAIR
  int2*  tops    = (int2*)(pairw + NPAIR);         // NTOK
  int*   posmap  = (int*)(tops + NTOK);            // NPAIR

  prep_kernel<<<GATE_BLOCKS + CVT_BLOCKS, 256, 0, stream>>>(
      (const float4*)w1, (ushort4*)w1_bf, x, gW, gb, gp, tops, pairw, cnt, x_bf, y);
  bin_sched_kernel<<<NBIN, 256, 0, stream>>>(tops, cnt, bucket, posmap, done,
                                             base, sched, sched_n);
  ffn_gemm<1, 1, 0><<<GRID, 256, 0, stream>>>(x_bf, w1_bf, b1, base, bucket, pairw,
                                              sched, sched_n, h_pack, nullptr);
  cvt_kernel<<<CVT_BLOCKS, 256, 0, stream>>>((const float4*)w2, (ushort4*)w2_bf);
  ffn_gemm<0, 0, 1><<<GRID, 256, 0, stream>>>(h_pack, w2_bf, b2, base, bucket, pairw,
                                              sched, sched_n, nullptr, y);
}

// Round 10
// 228.315 us; speedup vs baseline: 1.0399x; 1.0399x over previous
//
#include <hip/hip_runtime.h>

#define NTOK 4096
#define DIM 1024
#define NE 8
#define NPAIR (NTOK * 2)
#define GATE_BLOCKS (NTOK / 4)   // 1024
#define CVT_BLOCKS 8192          // one tensor: 8M float4 / 256 thr / 4 per thr
#define NBIN (NTOK / 256)        // 16
#define GRID 576                 // 8 xcd x 9 slots x 8 nt

typedef __bf16 bf16x8 __attribute__((ext_vector_type(8)));
typedef float floatx4 __attribute__((ext_vector_type(4)));

__device__ __forceinline__ unsigned short f2bf(float f) {
  unsigned u = __float_as_uint(f);
  u = u + 0x7fffu + ((u >> 16) & 1u);
  return (unsigned short)(u >> 16);
}
__device__ __forceinline__ float bf2f(unsigned short h) {
  return __uint_as_float(((unsigned)h) << 16);
}

__device__ __forceinline__ void gld_lds16(const unsigned short* g, unsigned short* l) {
  __builtin_amdgcn_global_load_lds(
      (const __attribute__((address_space(1))) void*)g,
      (__attribute__((address_space(3))) void*)l, 16, 0, 0);
}

// ---------------- prep: gate (blocks 0..1023, FIRST so bin's dep clears early) ---------
// + w1 cvt (blocks 1024..9215). Gate: one wave per token; emits x_bf, tops, pairw, gp.
// Block 0 zeroes cnt[0..7]+done.
__global__ __launch_bounds__(256) void prep_kernel(
    const float4* __restrict__ w1, ushort4* __restrict__ w1_bf,
    const float* __restrict__ x, const float* __restrict__ gW,
    const float* __restrict__ gb, float* __restrict__ gp_out,
    int2* __restrict__ tops, float* __restrict__ pairw,
    int* __restrict__ cnt, unsigned short* __restrict__ x_bf)
{
  const int tid = threadIdx.x;
  int b = blockIdx.x;
  if (b >= GATE_BLOCKS) {                     // -------- cvt w1 branch --------
    const int i = (b - GATE_BLOCKS) * 256 + tid;
    float4 v = w1[i];
    ushort4 o;
    o.x = f2bf(v.x); o.y = f2bf(v.y); o.z = f2bf(v.z); o.w = f2bf(v.w);
    w1_bf[i] = o;
    return;
  }
  // -------- gate branch (R2-proven) --------
  if (b == 0 && tid < NE + 1) cnt[tid] = 0;   // cnt[0..7] + done
  const int lane = tid & 63;
  const int wid = tid >> 6;
  const int t = b * 4 + wid;

  float4 xv[4];
#pragma unroll
  for (int j = 0; j < 4; j++)
    xv[j] = ((const float4*)(x + (size_t)t * DIM))[lane + 64 * j];

  // bf16 copy of the row (identical f2bf as the packed-A path)
#pragma unroll
  for (int j = 0; j < 4; j++) {
    ushort4 o;
    o.x = f2bf(xv[j].x); o.y = f2bf(xv[j].y);
    o.z = f2bf(xv[j].z); o.w = f2bf(xv[j].w);
    ((ushort4*)(x_bf + (size_t)t * DIM))[lane + 64 * j] = o;
  }

  float p[NE];
#pragma unroll
  for (int e = 0; e < NE; e++) {
    const float4* gwe = (const float4*)(gW + e * DIM);
    float s = 0.f;
#pragma unroll
    for (int j = 0; j < 4; j++) {
      float4 g = gwe[lane + 64 * j];
      s += xv[j].x * g.x + xv[j].y * g.y + xv[j].z * g.z + xv[j].w * g.w;
    }
    p[e] = s;
  }
#pragma unroll
  for (int e = 0; e < NE; e++) {
#pragma unroll
    for (int off = 32; off >= 1; off >>= 1) p[e] += __shfl_xor(p[e], off);
  }

  float m = -1e30f;
#pragma unroll
  for (int e = 0; e < NE; e++) { p[e] += gb[e]; m = fmaxf(m, p[e]); }
  float s = 0.f;
  float pr[NE];
#pragma unroll
  for (int e = 0; e < NE; e++) { pr[e] = __expf(p[e] - m); s += pr[e]; }
  float inv = 1.f / s;
#pragma unroll
  for (int e = 0; e < NE; e++) pr[e] *= inv;

  if (lane < NE) gp_out[(size_t)t * NE + lane] = pr[lane];

  if (lane == 0) {
    int i0 = 0;
#pragma unroll
    for (int e = 1; e < NE; e++) if (pr[e] > pr[i0]) i0 = e;
    int i1 = (i0 == 0) ? 1 : 0;
#pragma unroll
    for (int e = 0; e < NE; e++) if (e != i0 && pr[e] > pr[i1]) i1 = e;
    float d = __expf(pr[i1] - pr[i0]);
    float w0 = 1.f / (1.f + d);
    tops[t] = make_int2(i0, i1);
    pairw[t * 2] = w0;
    pairw[t * 2 + 1] = 1.f - w0;
  }
}

// ------- binning + schedule: wave-aggregated ballot atomics (R2-proven) ----------------
__global__ __launch_bounds__(256) void bin_sched_kernel(
    const int2* __restrict__ tops, int* __restrict__ cnt,
    int* __restrict__ bucket,      // [NE][NTOK]: pair id per within-expert index
    int* __restrict__ posmap,      // [NPAIR]: (e<<16)|idx for each (token,slot)
    int* __restrict__ done, int* __restrict__ base,   // base[9]
    int* __restrict__ sched, int* __restrict__ sched_n)
{
  const int t = blockIdx.x * 256 + threadIdx.x;
  const int lane = threadIdx.x & 63;
  int2 ti = tops[t];
#pragma unroll
  for (int slot = 0; slot < 2; slot++) {
    int e = slot ? ti.y : ti.x;
#pragma unroll
    for (int ex = 0; ex < NE; ex++) {
      bool mine = (e == ex);
      unsigned long long mask = __ballot(mine);
      if (mask) {
        int leader = __ffsll((long long)mask) - 1;
        int total = __popcll(mask);
        int prefix = __popcll(mask & ((1ull << lane) - 1ull));
        int idx = 0;
        if (lane == leader) idx = atomicAdd(&cnt[ex], total);
        idx = __shfl(idx, leader) + prefix;
        if (mine) {
          bucket[ex * NTOK + idx] = t * 2 + slot;
          posmap[t * 2 + slot] = (ex << 16) | idx;
        }
      }
    }
  }
  __syncthreads();
  if (threadIdx.x == 0) {
    if (atomicAdd(done, 1) == gridDim.x - 1) {   // last block: build schedule
      int b = 0, pos = 0;
      for (int e = 0; e < NE; e++) {
        int c = atomicAdd(&cnt[e], 0);           // device-coherent read
        base[e] = b;
        int tiles = (c + 127) >> 7;
        for (int i = 0; i < tiles; i++) {
          int valid = c - i * 128; if (valid > 128) valid = 128;
          sched[pos++] = (e << 20) | (i << 8) | valid;
        }
        b += c;
      }
      base[NE] = b;
      *sched_n = pos;
    }
  }
}

// ---------------- fp32 -> bf16 conversion of w2 (AFTER gemm1, into dead x_bf region) ---
__global__ __launch_bounds__(256) void cvt_kernel(
    const float4* __restrict__ src, ushort4* __restrict__ dst)
{
  const int i = blockIdx.x * 256 + threadIdx.x;
  float4 v = src[i];
  ushort4 o;
  o.x = f2bf(v.x); o.y = f2bf(v.y); o.z = f2bf(v.z); o.w = f2bf(v.w);
  dst[i] = o;
}

// -------- grouped GEMM: 128x128 tile, BK=64, single-buffer, 4 WAVES (R7-proven) --------
// Best measured across R0-R9 (41 µs, 409 TF). m97-style 2-barrier loop; implicit
// wave-level overlap across 2-3 resident blocks/CU does the latency hiding (m114).
// GATHER=1: A rows gathered from x_bf via bucket (gemm1); GATHER=0: packed rows.
template <int RELU, int GATHER>
__global__ __launch_bounds__(256) void ffn_gemm(
    const unsigned short* __restrict__ A,     // GATHER ? x_bf [NTOK][DIM] : packed [NPAIR][DIM]
    const unsigned short* __restrict__ B,     // [NE][DIM][DIM]
    const float* __restrict__ bias,           // [NE][DIM]
    const int* __restrict__ base,
    const int* __restrict__ bucket,
    const int* __restrict__ sched, const int* __restrict__ sched_n,
    unsigned short* __restrict__ Out)         // packed
{
  const int l = blockIdx.x;
  const int xcd = l & 7;
  const int w = l >> 3;
  const int nt = w & 7;
  const int slot = xcd * 9 + (w >> 3);
  if (slot >= *sched_n) return;
  const int se = sched[slot];
  const int e = se >> 20;
  const int mt = (se >> 8) & 0xfff;
  const int valid = se & 255;               // valid rows in this tile (1..128)
  const int arow0 = base[e] + mt * 128;

  __shared__ unsigned short lda[128 * 64];  // 16 KB
  __shared__ unsigned short ldb[128 * 64];  // 16 KB (32 KB total -> 5 blocks/CU cap)

  const int tid = threadIdx.x;
  const int lane = tid & 63;
  const int wid = tid >> 6;

  const unsigned short* ap[4];
  const unsigned short* bp[4];
#pragma unroll
  for (int j = 0; j < 4; j++) {
    int g = wid * 4 + j;
    int row = g * 8 + (lane >> 3);
    int gran = (lane & 7) ^ (row & 7);      // source-side XOR swizzle (0 conflicts)
    if (GATHER) {
      int idx = mt * 128 + row;             // within-expert index
      int ce = base[e + 1] - base[e];       // expert count (>=1 if tile exists)
      if (idx > ce - 1) idx = ce - 1;       // clamp pad rows (masked at store)
      int tok = bucket[e * NTOK + idx] >> 1;
      ap[j] = A + (size_t)tok * DIM + (gran << 3);
    } else {
      int prow = arow0 + row;
      if (prow > NPAIR - 1) prow = NPAIR - 1;
      ap[j] = A + (size_t)prow * DIM + (gran << 3);
    }
    bp[j] = B + ((size_t)e * DIM + nt * 128 + row) * DIM + (gran << 3);
  }

  floatx4 acc[4][4] = {};
  const int wm = (wid & 1) * 64;
  const int wn = (wid >> 1) * 64;
  const int quad = lane >> 4;
  const int cl = lane & 15;
  const int sw = cl & 7;

  for (int k0 = 0; k0 < 16; k0++) {
#pragma unroll
    for (int j = 0; j < 4; j++) {
      int g = wid * 4 + j;
      gld_lds16(ap[j], &lda[g * 512]);
      gld_lds16(bp[j], &ldb[g * 512]);
      ap[j] += 64;
      bp[j] += 64;
    }
    __syncthreads();
#pragma unroll
    for (int kk = 0; kk < 64; kk += 32) {
      const int gb = (kk >> 3) + quad;
      const int goff = ((gb ^ sw) << 3);
      bf16x8 af[4], bfr[4];
#pragma unroll
      for (int mi = 0; mi < 4; mi++)
        af[mi] = *(const bf16x8*)&lda[(wm + mi * 16 + cl) * 64 + goff];
#pragma unroll
      for (int ni = 0; ni < 4; ni++)
        bfr[ni] = *(const bf16x8*)&ldb[(wn + ni * 16 + cl) * 64 + goff];
#pragma unroll
      for (int mi = 0; mi < 4; mi++)
#pragma unroll
        for (int ni = 0; ni < 4; ni++)
          acc[mi][ni] = __builtin_amdgcn_mfma_f32_16x16x32_bf16(af[mi], bfr[ni], acc[mi][ni], 0, 0, 0);
    }
    if (k0 < 15) __syncthreads();
  }

  // epilogue: C/D layout col=lane&15, row=(lane>>4)*4+reg [m89]; sequential packed store
#pragma unroll
  for (int ni = 0; ni < 4; ni++) {
    int col = nt * 128 + wn + ni * 16 + cl;
    float bval = bias[e * DIM + col];
#pragma unroll
    for (int mi = 0; mi < 4; mi++) {
#pragma unroll
      for (int reg = 0; reg < 4; reg++) {
        int rl = wm + mi * 16 + quad * 4 + reg;
        if (rl < valid) {
          float v = acc[mi][ni][reg] + bval;
          if (RELU) v = fmaxf(v, 0.f);
          Out[(size_t)(arow0 + rl) * DIM + col] = f2bf(v);
        }
      }
    }
  }
}

// ---------------- combine: y[t] = w0*o[p0] + w1*o[p1] (gather via posmap) --------------
__global__ __launch_bounds__(256) void combine_kernel(
    const unsigned short* __restrict__ o, const int* __restrict__ posmap,
    const int* __restrict__ base, const float* __restrict__ pairw,
    float* __restrict__ y)
{
  const int t = blockIdx.x;
  const int tid = threadIdx.x;
  const int pm0 = posmap[t * 2], pm1 = posmap[t * 2 + 1];
  const int p0 = base[pm0 >> 16] + (pm0 & 0xffff);
  const int p1 = base[pm1 >> 16] + (pm1 & 0xffff);
  const float w0 = pairw[t * 2], w1 = pairw[t * 2 + 1];
  ushort4 a = ((const ushort4*)(o + (size_t)p0 * DIM))[tid];
  ushort4 b = ((const ushort4*)(o + (size_t)p1 * DIM))[tid];
  float4 r;
  r.x = w0 * bf2f(a.x) + w1 * bf2f(b.x);
  r.y = w0 * bf2f(a.y) + w1 * bf2f(b.y);
  r.z = w0 * bf2f(a.z) + w1 * bf2f(b.z);
  r.w = w0 * bf2f(a.w) + w1 * bf2f(b.w);
  ((float4*)(y + (size_t)t * DIM))[tid] = r;
}

extern "C" void kernel_launch(void* const* d_in, const int* in_sizes, int n_in,
                              void* d_out, int out_size, void* d_ws, size_t ws_size,
                              hipStream_t stream) {
  const float* x  = (const float*)d_in[0];
  const float* gW = (const float*)d_in[1];
  const float* gb = (const float*)d_in[2];
  const float* w1 = (const float*)d_in[3];
  const float* b1 = (const float*)d_in[4];
  const float* w2 = (const float*)d_in[5];
  const float* b2 = (const float*)d_in[6];
  float* y  = (float*)d_out;
  float* gp = (float*)d_out + (size_t)NTOK * DIM;

  // ws layout (bytes) — peak 48M + ~230K. Two staged aliases (stream-sequential):
  //  [0,16M):   x_bf (8M, prep->gemm1) -> dead after gemm1 -> w2_bf (cvt->gemm2 B)
  //  [16,32M):  w1_bf (prep->gemm1 B)  -> dead after gemm1 -> o_pack (gemm2 out)
  //  [32,48M):  h_pack (gemm1 out -> gemm2 A)
  //  [48M,..):  cnt|done|base|sched|sched_n|bucket|pairw|tops|posmap
  char* ws = (char*)d_ws;
  unsigned short* x_bf   = (unsigned short*)(ws);
  unsigned short* w2_bf  = (unsigned short*)(ws);                       // alias, post-gemm1
  unsigned short* w1_bf  = (unsigned short*)(ws + (size_t)(16u << 20));
  unsigned short* o_pack = (unsigned short*)(ws + (size_t)(16u << 20)); // alias, post-gemm1
  unsigned short* h_pack = (unsigned short*)(ws + (size_t)(32u << 20));
  char* tail = ws + (size_t)(48u << 20);
  int*   cnt     = (int*)(tail);                   // 8
  int*   done    = cnt + NE;                       // 1 (contiguous: cnt[8])
  int*   base    = done + 1;                       // 9
  int*   sched   = base + NE + 1;                  // <=256 (128-row tiles: up to 72)
  int*   sched_n = sched + 256;                    // 1
  int*   bucket  = sched_n + 1;                    // NE*NTOK
  float* pairw   = (float*)(bucket + NE * NTOK);   // NPAIR
  int2*  tops    = (int2*)(pairw + NPAIR);         // NTOK
  int*   posmap  = (int*)(tops + NTOK);            // NPAIR

  prep_kernel<<<GATE_BLOCKS + CVT_BLOCKS, 256, 0, stream>>>(
      (const float4*)w1, (ushort4*)w1_bf, x, gW, gb, gp, tops, pairw, cnt, x_bf);
  bin_sched_kernel<<<NBIN, 256, 0, stream>>>(tops, cnt, bucket, posmap, done,
                                             base, sched, sched_n);
  ffn_gemm<1, 1><<<GRID, 256, 0, stream>>>(x_bf, w1_bf, b1, base, bucket,
                                           sched, sched_n, h_pack);
  cvt_kernel<<<CVT_BLOCKS, 256, 0, stream>>>((const float4*)w2, (ushort4*)w2_bf);
  ffn_gemm<0, 0><<<GRID, 256, 0, stream>>>(h_pack, w2_bf, b2, base, bucket,
                                           sched, sched_n, o_pack);
  combine_kernel<<<NTOK, 256, 0, stream>>>(o_pack, posmap, base, pairw, y);
}